// Round 11
// baseline (98.944 us; speedup 1.0000x reference)
//
#include <hip/hip_runtime.h>

// LateralEI: out = GAIN * rownorm(K) @ h, K = 0.8*exp(-d2/0.72) - exp(-d2/2.88)
// z: [8192][2] f32, h: [8192][128] f32, out: [8192][128] f32
//
// R11: VALU-halving A/B against R8 (identical grid 1024x256, 4 blk/CU, same
// B pattern, same layouts). R8 counters: 43.3us, VALUBusy 40% (=17us issue,
// ~650 cyc/wave-iter), MfmaUtil 14%, HBM 3%, conflicts 0 => ~40% issue-bound
// with latency residue. R11 rewrites the w-core in PACKED fp32 (v_pk_fma_f32,
// full-rate on CDNA4) over k-pairs: z staged DEINTERLEAVED (zx/zy/az) into
// block-LDS once, so (k,k+1) pairs are register-adjacent f32x2. Loop vmem =
// only the 8 B-loads (compiler-tracked waits, no manual vmcnt). Per-wave-iter
// issue ~310 cyc (halved). All verified pieces unchanged: hTf fragment-major
// layout, truncation A-pack, 16x16x32 MFMA, C/D mapping, bf16 partials.

typedef float f32x4 __attribute__((ext_vector_type(4)));
typedef float f32x2 __attribute__((ext_vector_type(2)));
typedef short s16x8 __attribute__((ext_vector_type(8)));
typedef unsigned int u32x4 __attribute__((ext_vector_type(4)));

#define NPTS 8192
#define DH 128
#define A_I (-0.5009357781f)  // -log2(e)/(2*1.2^2); A_E = 4*A_I
#define GAIN_C 0.05f

#define NKS 16      // cross-block K-slices (512 k each)
#define KSL 512
#define NITER 16    // 512 / 32
#define NRT 64      // row-tiles (128 rows = 4 waves x 32)

// ---------- pre-pass: h [8192][128] f32 -> hTf fragment-major bf16 (R4-verified) ----------
__global__ __launch_bounds__(256) void h_to_hTf(
    const float* __restrict__ h, unsigned short* __restrict__ hTf) {
  __shared__ unsigned int tileW[DH * 17];  // [n][kp], kp = k-pair 0..15
  const int t = threadIdx.x;
  const int k5 = blockIdx.x;
  const int n = t & 127;
  const int g = t >> 7;  // 0..1
#pragma unroll
  for (int p = 0; p < 8; ++p) {
    const int kp = g * 8 + p;
    unsigned int a = __float_as_uint(h[(k5 * 32 + 2 * kp) * DH + n]);
    unsigned int b = __float_as_uint(h[(k5 * 32 + 2 * kp + 1) * DH + n]);
    a = (a + 0x7fffu + ((a >> 16) & 1u)) >> 16;          // RNE low half
    b = (b + 0x7fffu + ((b >> 16) & 1u)) & 0xffff0000u;  // RNE high half
    tileW[n * 17 + kp] = a | b;
  }
  __syncthreads();
#pragma unroll
  for (int it = 0; it < 2; ++it) {
    const int u = t + it * 256;
    const int cf = u >> 6;
    const int lane = u & 63;
    const int nf = lane & 15;
    const int q = lane >> 4;
    const int n2 = cf * 16 + nf;
    u32x4 val;
#pragma unroll
    for (int i = 0; i < 4; ++i) val[i] = tileW[n2 * 17 + q * 4 + i];
    *(u32x4*)(hTf + k5 * 4096 + u * 8) = val;
  }
}

// ---------- main fused kernel ----------
__global__ __launch_bounds__(256, 4) void lateral_ei_main(
    const float* __restrict__ z, const unsigned short* __restrict__ hTf,
    unsigned short* __restrict__ partb, float* __restrict__ prs) {
  __shared__ __align__(16) float zxs[KSL];  // x, deinterleaved
  __shared__ __align__(16) float zys[KSL];  // y
  __shared__ __align__(16) float zas[KSL];  // A_I*|z_k|^2

  const int t = threadIdx.x;
  const int lane = t & 63;
  const int w = t >> 6;  // wave 0..3
  const int rt = blockIdx.x & (NRT - 1);
  const int ks = blockIdx.x >> 6;  // 0..NKS-1
  const int i0 = rt * 128 + w * 32;
  const int nf = lane & 15;
  const int q = lane >> 4;
  const int k0 = ks * KSL;

  // zi constants for rows i0+nf (rg0), i0+16+nf (rg1) — splat to f32x2
  const float zx0 = z[(i0 + nf) * 2], zy0 = z[(i0 + nf) * 2 + 1];
  const float zx1 = z[(i0 + 16 + nf) * 2], zy1 = z[(i0 + 16 + nf) * 2 + 1];
  const f32x2 cA2[2] = {{A_I * (zx0 * zx0 + zy0 * zy0), A_I * (zx0 * zx0 + zy0 * zy0)},
                        {A_I * (zx1 * zx1 + zy1 * zy1), A_I * (zx1 * zx1 + zy1 * zy1)}};
  const f32x2 cX2[2] = {{-2.f * A_I * zx0, -2.f * A_I * zx0},
                        {-2.f * A_I * zx1, -2.f * A_I * zx1}};
  const f32x2 cY2[2] = {{-2.f * A_I * zy0, -2.f * A_I * zy0},
                        {-2.f * A_I * zy1, -2.f * A_I * zy1}};

  // ---- preamble: stage z slice deinterleaved into LDS (2 pts/thread) ----
  {
    const int k2 = t * 2;
    const f32x4 p = *(const f32x4*)(z + (size_t)(k0 + k2) * 2);  // x0,y0,x1,y1
    *(f32x2*)(zxs + k2) = (f32x2){p[0], p[2]};
    *(f32x2*)(zys + k2) = (f32x2){p[1], p[3]};
    *(f32x2*)(zas + k2) =
        (f32x2){A_I * fmaf(p[1], p[1], p[0] * p[0]), A_I * fmaf(p[3], p[3], p[2] * p[2])};
  }
  __syncthreads();

  // B fragment base (R4-verified hTf layout)
  const unsigned short* hb = hTf + (size_t)(ks * 16) * 4096 + lane * 8;

  f32x4 acc0[8], acc1[8];
#pragma unroll
  for (int cf = 0; cf < 8; ++cf) {
    acc0[cf] = (f32x4){0.f, 0.f, 0.f, 0.f};
    acc1[cf] = (f32x4){0.f, 0.f, 0.f, 0.f};
  }
  f32x2 rsp[2] = {{0.f, 0.f}, {0.f, 0.f}};

#pragma unroll 1
  for (int it = 0; it < NITER; ++it) {
    // ---- issue the 8 coalesced B-loads (loop's only vmem; in flight over math)
    s16x8 bfr[8];
#pragma unroll
    for (int cf = 0; cf < 8; ++cf)
      bfr[cf] = *(const s16x8*)(hb + it * 4096 + cf * 512);

    // ---- z for this iter's 8 k's: quad-uniform LDS broadcast reads
    const int kb = it * 32 + q * 8;
    const f32x4 X0 = *(const f32x4*)(zxs + kb);
    const f32x4 X1 = *(const f32x4*)(zxs + kb + 4);
    const f32x4 Y0 = *(const f32x4*)(zys + kb);
    const f32x4 Y1 = *(const f32x4*)(zys + kb + 4);
    const f32x4 Az0 = *(const f32x4*)(zas + kb);
    const f32x4 Az1 = *(const f32x4*)(zas + kb + 4);

    // ---- packed w-production: 4 k-pairs x 2 row-groups (v_pk_fma_f32 path)
    unsigned int afu[2][4];
#pragma unroll
    for (int j2 = 0; j2 < 4; ++j2) {
      const int e = (j2 & 1) * 2;
      const f32x2 xp = (j2 < 2) ? (f32x2){X0[e], X0[e + 1]} : (f32x2){X1[e], X1[e + 1]};
      const f32x2 yp = (j2 < 2) ? (f32x2){Y0[e], Y0[e + 1]} : (f32x2){Y1[e], Y1[e + 1]};
      const f32x2 ap = (j2 < 2) ? (f32x2){Az0[e], Az0[e + 1]} : (f32x2){Az1[e], Az1[e + 1]};
#pragma unroll
      for (int rg = 0; rg < 2; ++rg) {
        const f32x2 base = ap + cA2[rg];
        const f32x2 u = __builtin_elementwise_fma(
            cX2[rg], xp, __builtin_elementwise_fma(cY2[rg], yp, base));
        const f32x2 ei = {__builtin_amdgcn_exp2f(u[0]), __builtin_amdgcn_exp2f(u[1])};
        const f32x2 s = ei * ei;
        const f32x2 s2 = s * s;
        const f32x2 wv = __builtin_elementwise_fma(s2, (f32x2){0.8f, 0.8f}, -ei);
        rsp[rg] += wv;
        afu[rg][j2] = __builtin_amdgcn_perm(__float_as_uint(wv[1]),
                                            __float_as_uint(wv[0]), 0x07060302);
      }
    }

    // ---- 16 MFMAs
    union { unsigned int u[4]; s16x8 v; } af0, af1;
#pragma unroll
    for (int p = 0; p < 4; ++p) { af0.u[p] = afu[0][p]; af1.u[p] = afu[1][p]; }
    const s16x8 a0 = af0.v, a1 = af1.v;
#pragma unroll
    for (int cf = 0; cf < 8; ++cf) {
      acc0[cf] = __builtin_amdgcn_mfma_f32_16x16x32_bf16(a0, bfr[cf], acc0[cf], 0, 0, 0);
      acc1[cf] = __builtin_amdgcn_mfma_f32_16x16x32_bf16(a1, bfr[cf], acc1[cf], 0, 0, 0);
    }
  }

  // ---- rowsum: sum 4 quad-partials per row (lanes nf,nf+16,nf+32,nf+48)
  float rs0 = rsp[0][0] + rsp[0][1], rs1 = rsp[1][0] + rsp[1][1];
  rs0 += __shfl_xor(rs0, 16);
  rs0 += __shfl_xor(rs0, 32);
  rs1 += __shfl_xor(rs1, 16);
  rs1 += __shfl_xor(rs1, 32);
  if (lane < 16) {
    prs[ks * NPTS + i0 + nf] = rs0;
    prs[ks * NPTS + i0 + 16 + nf] = rs1;
  }

  // ---- partial store, bf16 RNE (C/D layout: col=cf*16+nf, row=q*4+r)
  unsigned short* pb = partb + (size_t)ks * (NPTS * DH);
#pragma unroll
  for (int cf = 0; cf < 8; ++cf)
#pragma unroll
    for (int r = 0; r < 4; ++r) {
      unsigned int u0 = __float_as_uint(acc0[cf][r]);
      unsigned int u1 = __float_as_uint(acc1[cf][r]);
      u0 = (u0 + 0x7fffu + ((u0 >> 16) & 1u)) >> 16;
      u1 = (u1 + 0x7fffu + ((u1 >> 16) & 1u)) >> 16;
      pb[(i0 + q * 4 + r) * DH + cf * 16 + nf] = (unsigned short)u0;
      pb[(i0 + 16 + q * 4 + r) * DH + cf * 16 + nf] = (unsigned short)u1;
    }
}

// ---------- reduce NKS K-slice partials + normalize + scale ----------
__global__ __launch_bounds__(256) void reduce_scale(
    const unsigned short* __restrict__ partb, const float* __restrict__ prs,
    float* __restrict__ out) {
  const int gid = blockIdx.x * 256 + threadIdx.x;  // 8 cols each
  const int base = gid * 8;
  const int row = gid >> 4;
  float c[8] = {0.f, 0.f, 0.f, 0.f, 0.f, 0.f, 0.f, 0.f};
  float rsum = 0.f;
#pragma unroll
  for (int s = 0; s < NKS; ++s) {
    const u32x4 v = *(const u32x4*)(partb + (size_t)s * (NPTS * DH) + base);
#pragma unroll
    for (int i = 0; i < 4; ++i) {
      c[2 * i] += __uint_as_float(v[i] << 16);
      c[2 * i + 1] += __uint_as_float(v[i] & 0xffff0000u);
    }
    rsum += prs[s * NPTS + row];
  }
  const float scl = GAIN_C / (rsum + 1e-6f);
  f32x4 o0 = {c[0] * scl, c[1] * scl, c[2] * scl, c[3] * scl};
  f32x4 o1 = {c[4] * scl, c[5] * scl, c[6] * scl, c[7] * scl};
  *(f32x4*)(out + base) = o0;
  *(f32x4*)(out + base + 4) = o1;
}

extern "C" void kernel_launch(void* const* d_in, const int* in_sizes, int n_in,
                              void* d_out, int out_size, void* d_ws, size_t ws_size,
                              hipStream_t stream) {
  (void)in_sizes; (void)n_in; (void)out_size; (void)ws_size;
  const float* z = (const float*)d_in[0];
  const float* h = (const float*)d_in[1];
  float* out = (float*)d_out;
  unsigned short* hTf = (unsigned short*)d_ws;                          // 2 MiB
  unsigned short* partb = (unsigned short*)((char*)d_ws + (2u << 20));  // 32 MiB bf16
  float* prs = (float*)((char*)d_ws + (34u << 20));                     // 512 KiB

  h_to_hTf<<<NPTS / 32, 256, 0, stream>>>(h, hTf);
  lateral_ei_main<<<NRT * NKS, 256, 0, stream>>>(z, hTf, partb, prs);
  reduce_scale<<<(NPTS * DH / 8) / 256, 256, 0, stream>>>(partb, prs, out);
}